// Round 1
// 717.396 us; speedup vs baseline: 1.1134x; 1.1134x over previous
//
#include <hip/hip_runtime.h>

#define N_EDGES 250000
#define N_ATOMS 10000

// ---------------------------------------------------------------------------
// Helpers: force wave-uniform values into SGPRs.
// ---------------------------------------------------------------------------
__device__ __forceinline__ int rfl_i(int x) {
    return __builtin_amdgcn_readfirstlane(x);
}
__device__ __forceinline__ float rfl_f(float x) {
    return __uint_as_float(__builtin_amdgcn_readfirstlane(__float_as_uint(x)));
}

// ---------------------------------------------------------------------------
// Bucketing: per-center edge lists. fill_list also packs (edge, neighbor) and
// the 16 sh values in ELIST ORDER so the density loop reads them sequentially
// (no gather, no dependent chain for sh).
// ---------------------------------------------------------------------------

__global__ void zero_counts_kernel(int* __restrict__ counts) {
    int i = blockIdx.x * blockDim.x + threadIdx.x;
    if (i < N_ATOMS) counts[i] = 0;
}

__global__ void count_edges_kernel(const int* __restrict__ centers,
                                   int* __restrict__ counts) {
    int e = blockIdx.x * blockDim.x + threadIdx.x;
    if (e < N_EDGES) atomicAdd(&counts[centers[e]], 1);
}

// Single-block exclusive scan over N_ATOMS counts -> offsets[0..N_ATOMS]
// (also writes a second copy "cursor" used as the fill cursor).
__global__ void scan_offsets_kernel(const int* __restrict__ counts,
                                    int* __restrict__ offsets,
                                    int* __restrict__ cursor) {
    __shared__ int sdata[256];
    const int t = threadIdx.x;
    const int CH = 40;  // ceil(10000/256)
    const int base = t * CH;
    int sum = 0;
    for (int i = 0; i < CH; ++i) {
        int idx = base + i;
        if (idx < N_ATOMS) sum += counts[idx];
    }
    sdata[t] = sum;
    __syncthreads();
    for (int off = 1; off < 256; off <<= 1) {
        int v = (t >= off) ? sdata[t - off] : 0;
        __syncthreads();
        sdata[t] += v;
        __syncthreads();
    }
    int incl = sdata[t];
    int run = incl - sum;  // exclusive prefix
    for (int i = 0; i < CH; ++i) {
        int idx = base + i;
        if (idx < N_ATOMS) {
            offsets[idx] = run;
            cursor[idx] = run;
            run += counts[idx];
        }
    }
    if (t == 255) offsets[N_ATOMS] = incl;  // total == N_EDGES
}

__global__ void fill_list_kernel(const int* __restrict__ centers,
                                 const int* __restrict__ neighbors,
                                 const float* __restrict__ sh0,
                                 const float* __restrict__ sh1,
                                 const float* __restrict__ sh2,
                                 const float* __restrict__ sh3,
                                 int* __restrict__ cursor,
                                 int2* __restrict__ elist2,
                                 float4* __restrict__ shp) {
    int e = blockIdx.x * blockDim.x + threadIdx.x;
    if (e >= N_EDGES) return;
    int p = atomicAdd(&cursor[centers[e]], 1);
    elist2[p] = make_int2(e, neighbors[e]);
    // Pack sh row: [sh0 | sh1[0..2] | sh2[0..4] | sh3[0..6]] = 16 floats, 64B.
    float4 va, vb, vc, vd;
    va.x = sh0[e];
    const float* s1 = sh1 + 3 * (size_t)e;
    va.y = s1[0]; va.z = s1[1]; va.w = s1[2];
    const float* s2 = sh2 + 5 * (size_t)e;
    vb.x = s2[0]; vb.y = s2[1]; vb.z = s2[2]; vb.w = s2[3];
    vc.x = s2[4];
    const float* s3 = sh3 + 7 * (size_t)e;
    vc.y = s3[0]; vc.z = s3[1]; vc.w = s3[2];
    vd.x = s3[3]; vd.y = s3[4]; vd.z = s3[5]; vd.w = s3[6];
    float4* o = shp + (size_t)p * 4;
    o[0] = va; o[1] = vb; o[2] = vc; o[3] = vd;
}

// ---------------------------------------------------------------------------
// Density kernel v2:
//   - 2 waves per atom (even/odd edges of the atom's elist), LDS pairwise
//     reduce at the end. Block = 256 threads = 2 atoms.
//   - Per iteration: sequential uniform reads of elist2[i] / shp[i] (chain
//     depth 0-1), then 11 saddr-form vector loads (emb b128 + 3 dwords,
//     rb0 b128, rb1 x3, rb2 x2, rb3 x1). sh values readfirstlane'd to SGPRs.
//   - l=0 ownership is BLOCKED: lane t owns channels 4t..4t+3 (float4 loads
//     and float4 output stores). l=1..3 stay interleaved (t + 64j).
// ---------------------------------------------------------------------------

__global__ __launch_bounds__(256) void density_kernel(
    const float* __restrict__ rb0, const float* __restrict__ rb1,
    const float* __restrict__ rb2, const float* __restrict__ rb3,
    const float* __restrict__ emb, const int* __restrict__ offsets,
    const int2* __restrict__ elist2, const float4* __restrict__ shp,
    float* __restrict__ out) {
    __shared__ float red[2][1920];  // one 1920-f32 output image per atom slot

    const int wave = threadIdx.x >> 6;  // 0..3
    const int pairidx = wave >> 1;      // atom slot within block: 0,1
    const int sub = wave & 1;           // 0: primary (reduces+writes), 1: secondary
    const int a = blockIdx.x * 2 + pairidx;  // grid = 5000 -> a < 10000
    const int t = threadIdx.x & 63;

    const int s = rfl_i(offsets[a]);
    const int e = rfl_i(offsets[a + 1]);

    float4 a0 = {0.f, 0.f, 0.f, 0.f};
    float a1[3][3] = {};
    float a2[5][2] = {};
    float a3[7] = {};

    for (int i = s + sub; i < e; i += 2) {
        // Sequential, wave-uniform reads (position-indexed; no gather).
        const int2 en = elist2[i];
        const int eg = rfl_i(en.x);
        const int nb = rfl_i(en.y);

        const float4 sv0 = shp[(size_t)i * 4 + 0];
        const float4 sv1 = shp[(size_t)i * 4 + 1];
        const float4 sv2 = shp[(size_t)i * 4 + 2];
        const float4 sv3 = shp[(size_t)i * 4 + 3];

        // emb row: float4 (blocked, l=0) + 3 dwords (interleaved, l=1..3);
        // the dwords hit the same L1 lines as the wave's float4 coverage.
        const float* er = emb + ((size_t)nb << 8);
        const float4 em4 = *(const float4*)(er + 4 * t);
        const float emA = er[t];
        const float emB = er[t + 64];
        const float emC = er[t + 128];

        const float4 r04 = *(const float4*)(rb0 + ((size_t)eg << 8) + 4 * t);
        const float* r1p = rb1 + (size_t)eg * 192;
        const float r1A = r1p[t], r1B = r1p[t + 64], r1C = r1p[t + 128];
        const float* r2p = rb2 + ((size_t)eg << 7);
        const float r2A = r2p[t], r2B = r2p[t + 64];
        const float r3A = rb3[((size_t)eg << 6) + t];

        // rb * emb products
        const float p0x = r04.x * em4.x, p0y = r04.y * em4.y;
        const float p0z = r04.z * em4.z, p0w = r04.w * em4.w;
        const float pA = r1A * emA, pB = r1B * emB, pC = r1C * emC;
        const float qA = r2A * emA, qB = r2B * emB;
        const float v3 = r3A * emA;

        // sh values -> SGPRs (saves ~16 VGPRs; v_fmac takes one SGPR operand)
        const float s0 = rfl_f(sv0.x);
        a0.x += s0 * p0x; a0.y += s0 * p0y; a0.z += s0 * p0z; a0.w += s0 * p0w;

        const float sh1v[3] = {rfl_f(sv0.y), rfl_f(sv0.z), rfl_f(sv0.w)};
#pragma unroll
        for (int m = 0; m < 3; ++m) {
            a1[m][0] += sh1v[m] * pA;
            a1[m][1] += sh1v[m] * pB;
            a1[m][2] += sh1v[m] * pC;
        }
        const float sh2v[5] = {rfl_f(sv1.x), rfl_f(sv1.y), rfl_f(sv1.z),
                               rfl_f(sv1.w), rfl_f(sv2.x)};
#pragma unroll
        for (int m = 0; m < 5; ++m) {
            a2[m][0] += sh2v[m] * qA;
            a2[m][1] += sh2v[m] * qB;
        }
        const float sh3v[7] = {rfl_f(sv2.y), rfl_f(sv2.z), rfl_f(sv2.w),
                               rfl_f(sv3.x), rfl_f(sv3.y), rfl_f(sv3.z),
                               rfl_f(sv3.w)};
#pragma unroll
        for (int m = 0; m < 7; ++m) a3[m] += sh3v[m] * v3;
    }

    // Pairwise reduce across the atom's two waves via LDS.
    // Flat per-atom layout: [0,256)=l0 | [256,832)=l1 | [832,1472)=l2 | [1472,1920)=l3
    float* R = red[pairidx];
    if (sub == 1) {
        reinterpret_cast<float4*>(R)[t] = a0;  // ch 4t..4t+3
#pragma unroll
        for (int m = 0; m < 3; ++m)
#pragma unroll
            for (int j = 0; j < 3; ++j) R[256 + m * 192 + 64 * j + t] = a1[m][j];
#pragma unroll
        for (int m = 0; m < 5; ++m)
#pragma unroll
            for (int j = 0; j < 2; ++j) R[832 + m * 128 + 64 * j + t] = a2[m][j];
#pragma unroll
        for (int m = 0; m < 7; ++m) R[1472 + m * 64 + t] = a3[m];
    }
    __syncthreads();
    if (sub == 0) {
        const float4 rv = reinterpret_cast<const float4*>(R)[t];
        a0.x += rv.x; a0.y += rv.y; a0.z += rv.z; a0.w += rv.w;
#pragma unroll
        for (int m = 0; m < 3; ++m)
#pragma unroll
            for (int j = 0; j < 3; ++j) a1[m][j] += R[256 + m * 192 + 64 * j + t];
#pragma unroll
        for (int m = 0; m < 5; ++m)
#pragma unroll
            for (int j = 0; j < 2; ++j) a2[m][j] += R[832 + m * 128 + 64 * j + t];
#pragma unroll
        for (int m = 0; m < 7; ++m) a3[m] += R[1472 + m * 64 + t];

        // Output: concat of [10000,1,256], [10000,3,192], [10000,5,128],
        // [10000,7,64] flat f32.
        const size_t O1 = (size_t)N_ATOMS * 256;
        const size_t O2 = O1 + (size_t)N_ATOMS * 3 * 192;
        const size_t O3 = O2 + (size_t)N_ATOMS * 5 * 128;

        float* o0 = out + (size_t)a * 256;
        reinterpret_cast<float4*>(o0)[t] = a0;  // ch 4t..4t+3

        float* o1 = out + O1 + (size_t)a * 3 * 192;
#pragma unroll
        for (int m = 0; m < 3; ++m)
#pragma unroll
            for (int j = 0; j < 3; ++j) o1[m * 192 + 64 * j + t] = a1[m][j];

        float* o2 = out + O2 + (size_t)a * 5 * 128;
#pragma unroll
        for (int m = 0; m < 5; ++m)
#pragma unroll
            for (int j = 0; j < 2; ++j) o2[m * 128 + 64 * j + t] = a2[m][j];

        float* o3 = out + O3 + (size_t)a * 7 * 64;
#pragma unroll
        for (int m = 0; m < 7; ++m) o3[m * 64 + t] = a3[m];
    }
}

// ---------------------------------------------------------------------------

extern "C" void kernel_launch(void* const* d_in, const int* in_sizes, int n_in,
                              void* d_out, int out_size, void* d_ws, size_t ws_size,
                              hipStream_t stream) {
    // Input order = setup_inputs() dict INSERTION order:
    //   0: sh_0 [250000,1,1]   1: rb_0 [250000,256]
    //   2: sh_1 [250000,3,1]   3: rb_1 [250000,192]
    //   4: sh_2 [250000,5,1]   5: rb_2 [250000,128]
    //   6: sh_3 [250000,7,1]   7: rb_3 [250000,64]
    //   8: emb  [10000,1,256]  9: centers [250000]  10: neighbors [250000]
    const float* sh0 = (const float*)d_in[0];
    const float* rb0 = (const float*)d_in[1];
    const float* sh1 = (const float*)d_in[2];
    const float* rb1 = (const float*)d_in[3];
    const float* sh2 = (const float*)d_in[4];
    const float* rb2 = (const float*)d_in[5];
    const float* sh3 = (const float*)d_in[6];
    const float* rb3 = (const float*)d_in[7];
    const float* emb = (const float*)d_in[8];
    const int* centers = (const int*)d_in[9];
    const int* neighbors = (const int*)d_in[10];
    float* out = (float*)d_out;

    // Workspace layout (18,120,004 bytes total):
    //   shp    : float4[250000*4]  = 16,000,000 B   (16-B aligned at base)
    //   elist2 : int2[250000]      =  2,000,000 B   (8-B aligned)
    //   counts : int[10000]
    //   offsets: int[10001]
    //   cursor : int[10000]
    float4* shp = (float4*)d_ws;
    int2* elist2 = (int2*)((char*)d_ws + 16000000);
    int* counts = (int*)((char*)d_ws + 18000000);
    int* offsets = counts + N_ATOMS;
    int* cursor = offsets + (N_ATOMS + 1);

    zero_counts_kernel<<<(N_ATOMS + 255) / 256, 256, 0, stream>>>(counts);
    count_edges_kernel<<<(N_EDGES + 255) / 256, 256, 0, stream>>>(centers, counts);
    scan_offsets_kernel<<<1, 256, 0, stream>>>(counts, offsets, cursor);
    fill_list_kernel<<<(N_EDGES + 255) / 256, 256, 0, stream>>>(
        centers, neighbors, sh0, sh1, sh2, sh3, cursor, elist2, shp);
    density_kernel<<<N_ATOMS / 2, 256, 0, stream>>>(
        rb0, rb1, rb2, rb3, emb, offsets, elist2, shp, out);
}